// Round 1
// baseline (80.869 us; speedup 1.0000x reference)
//
#include <hip/hip_runtime.h>

// DifferentiableSMMPC: the reference iterates u <- u - Q_uu_inv @ (2 R u)
// starting from u = 0. Zero is a fixed point of that map, so the output
// u_traj[:, 0] is exactly zeros of shape (B=2048, D=128) -> 262144 f32.
// The kernel therefore only needs to zero d_out (harness poisons it to 0xAA
// before every timed launch, so the write must happen every call).

__global__ void __launch_bounds__(256)
smmpc_zero_out(float4* __restrict__ out, int n4) {
    int i = blockIdx.x * blockDim.x + threadIdx.x;
    if (i < n4) {
        out[i] = make_float4(0.f, 0.f, 0.f, 0.f);
    }
}

extern "C" void kernel_launch(void* const* d_in, const int* in_sizes, int n_in,
                              void* d_out, int out_size, void* d_ws, size_t ws_size,
                              hipStream_t stream) {
    (void)d_in; (void)in_sizes; (void)n_in; (void)d_ws; (void)ws_size;
    // out_size = 2048 * 128 = 262144 floats, divisible by 4.
    int n4 = out_size / 4;                 // 65536 float4 stores
    int block = 256;
    int grid = (n4 + block - 1) / block;   // 256 blocks
    smmpc_zero_out<<<grid, block, 0, stream>>>((float4*)d_out, n4);
}